// Round 7
// baseline (283.162 us; speedup 1.0000x reference)
//
#include <hip/hip_runtime.h>
#include <stdint.h>

typedef unsigned short u16;
typedef __bf16 bf16x8 __attribute__((ext_vector_type(8)));
typedef unsigned short u16x8 __attribute__((ext_vector_type(8)));
typedef float f32x4 __attribute__((ext_vector_type(4)));

#define LOG2E 1.4426950408889634f

// float -> bf16 round-to-nearest-even
__device__ __forceinline__ u16 f2bf(float f) {
  union { float f; uint32_t i; } v; v.f = f;
  uint32_t r = (v.i + 0x7fffu + ((v.i >> 16) & 1u)) >> 16;
  return (u16)r;
}
__device__ __forceinline__ float bf2f(u16 u) {
  union { uint32_t i; float f; } v; v.i = ((uint32_t)u) << 16; return v.f;
}

// ---------------------------------------------------------------------------
// Kernel 0: f32 -> bf16 convert (inputs are float32 per the reference).
// ---------------------------------------------------------------------------
__global__ __launch_bounds__(256) void f32_to_bf16(
    const float* __restrict__ x, const float* __restrict__ wq,
    const float* __restrict__ wk, const float* __restrict__ wv,
    u16* __restrict__ xc, u16* __restrict__ wqc,
    u16* __restrict__ wkc, u16* __restrict__ wvc) {
  const int z = blockIdx.y;
  const float* src = z == 0 ? x : (z == 1 ? wq : (z == 2 ? wk : wv));
  u16* dst = z == 0 ? xc : (z == 1 ? wqc : (z == 2 ? wkc : wvc));
  const int n = z == 0 ? (1 << 22) : (1 << 20);

  const int idx = (blockIdx.x * 256 + (int)threadIdx.x) * 8;
  if (idx >= n) return;
  const f32x4 a = *(const f32x4*)&src[idx];
  const f32x4 b = *(const f32x4*)&src[idx + 4];
  u16x8 o;
#pragma unroll
  for (int j = 0; j < 4; j++) { o[j] = f2bf(a[j]); o[j + 4] = f2bf(b[j]); }
  *(u16x8*)&dst[idx] = o;
}

// ---------------------------------------------------------------------------
// Kernel 1: QKV GEMM (x @ W^T), bf16 out to workspace.
// 128x128 tile, BK=32, verified m97-style structure.
// ---------------------------------------------------------------------------
__global__ __launch_bounds__(256) void qkv_gemm(
    const u16* __restrict__ x, const u16* __restrict__ Wq,
    const u16* __restrict__ Wk, const u16* __restrict__ Wv,
    u16* __restrict__ qo, u16* __restrict__ ko, u16* __restrict__ vo) {
  __shared__ __align__(16) u16 As[128 * 32];
  __shared__ __align__(16) u16 Bs[128 * 32];

  const int tid = threadIdx.x;
  const int lane = tid & 63;
  const int w = tid >> 6;
  const int wm = w >> 1, wn = w & 1;
  const int quad = lane >> 4, m16 = lane & 15;
  const int n0 = blockIdx.x * 128;
  const int m0 = blockIdx.y * 128;
  const int which = blockIdx.z;
  const u16* __restrict__ W = which == 0 ? Wq : (which == 1 ? Wk : Wv);
  u16* __restrict__ out = which == 0 ? qo : (which == 1 ? ko : vo);

  const f32x4 z4 = {0.f, 0.f, 0.f, 0.f};
  f32x4 acc[4][4];
#pragma unroll
  for (int i = 0; i < 4; i++)
#pragma unroll
    for (int j = 0; j < 4; j++) acc[i][j] = z4;

  const int rowA = m0 + w * 32 + (lane >> 2);
  const int rowB = n0 + w * 32 + (lane >> 2);
  const int cch = (lane & 3) * 8;

  for (int k0 = 0; k0 < 1024; k0 += 32) {
    u16x8 ra[2], rb[2];
#pragma unroll
    for (int i = 0; i < 2; i++) {
      ra[i] = *(const u16x8*)&x[(size_t)(rowA + i * 16) * 1024 + k0 + cch];
      rb[i] = *(const u16x8*)&W[(size_t)(rowB + i * 16) * 1024 + k0 + cch];
    }
    __syncthreads();
#pragma unroll
    for (int i = 0; i < 2; i++) {
      *(u16x8*)&As[(w * 32 + i * 16) * 32 + lane * 8] = ra[i];
      *(u16x8*)&Bs[(w * 32 + i * 16) * 32 + lane * 8] = rb[i];
    }
    __syncthreads();

    bf16x8 af[4], bfr[4];
#pragma unroll
    for (int t = 0; t < 4; t++) {
      af[t]  = *(const bf16x8*)&As[(wm * 64 + t * 16 + m16) * 32 + quad * 8];
      bfr[t] = *(const bf16x8*)&Bs[(wn * 64 + t * 16 + m16) * 32 + quad * 8];
    }
#pragma unroll
    for (int mt = 0; mt < 4; mt++)
#pragma unroll
      for (int nt = 0; nt < 4; nt++)
        acc[mt][nt] = __builtin_amdgcn_mfma_f32_16x16x32_bf16(
            af[mt], bfr[nt], acc[mt][nt], 0, 0, 0);
  }

  // C/D layout: col(n)=lane&15, row(m)=quad*4+reg (m89-verified).
#pragma unroll
  for (int mt = 0; mt < 4; mt++) {
    const int row = m0 + wm * 64 + mt * 16 + quad * 4;
#pragma unroll
    for (int nt = 0; nt < 4; nt++) {
      const int n = n0 + wn * 64 + nt * 16 + m16;
      f32x4 a = acc[mt][nt];
#pragma unroll
      for (int r = 0; r < 4; r++)
        out[(size_t)(row + r) * 1024 + n] = f2bf(a[r]);
    }
  }
}

// ---------------------------------------------------------------------------
// Kernel 2: standalone RoPE, in-place on q/k. One thread per (even,odd) pair.
// ---------------------------------------------------------------------------
__global__ __launch_bounds__(256) void rope_inplace(u16* __restrict__ qb,
                                                    u16* __restrict__ kb) {
  u16* buf = blockIdx.y == 0 ? qb : kb;
  const int p = blockIdx.x * 256 + (int)threadIdx.x;  // pair index
  const int nidx = p * 2;
  const int row = nidx >> 10;        // 0..4095
  const int col = nidx & 1023;       // even
  const int d = col & 63;            // dim within head (even)
  const int i = d >> 1;              // pair index within head, 0..31
  const int t = row & 2047;          // position
  const float theta = exp2f(-(float)i * 0.02595256324130752f);  // 10000^(-2i/1024)
  const float ang = (float)t * theta;
  float s, c;
  sincosf(ang, &s, &c);
  const float a0 = bf2f(buf[(size_t)row * 1024 + col]);
  const float a1 = bf2f(buf[(size_t)row * 1024 + col + 1]);
  buf[(size_t)row * 1024 + col]     = f2bf(a0 * c - a1 * s);
  buf[(size_t)row * 1024 + col + 1] = f2bf(a1 * c + a0 * s);
}

// ---------------------------------------------------------------------------
// Kernel 3: causal flash attention (R4 structure, staging-fixed), f32 output.
// Block = (q-tile 64) x head x batch, 4 waves; wave w owns q rows
// [w*16, w*16+16). K/V tiles of 64. LDS stride 72 elems.
// ---------------------------------------------------------------------------
__global__ __launch_bounds__(256) void flash_attn(
    const u16* __restrict__ qg, const u16* __restrict__ kg,
    const u16* __restrict__ vg, float* __restrict__ out) {
  __shared__ __align__(16) u16 Qs[64 * 72];
  __shared__ __align__(16) u16 Ks[64 * 72];
  __shared__ __align__(16) u16 Vs[64 * 72];  // transposed: [d][key]
  __shared__ __align__(16) u16 Ps[64 * 72];

  const int tid = threadIdx.x, lane = tid & 63, w = tid >> 6;
  const int quad = lane >> 4, m16 = lane & 15;
  const int qt = blockIdx.x, h = blockIdx.y, b = blockIdx.z;
  const int q0 = qt * 64;
  const size_t base = (size_t)b * 2048 * 1024 + (size_t)h * 64;

  {  // stage Q tile (64 rows x 64 dims): 256 thr x 16 elems each
    const int row = tid >> 2, c = (tid & 3) * 16;
    *(u16x8*)&Qs[row * 72 + c] =
        *(const u16x8*)&qg[base + (size_t)(q0 + row) * 1024 + c];
    *(u16x8*)&Qs[row * 72 + c + 8] =
        *(const u16x8*)&qg[base + (size_t)(q0 + row) * 1024 + c + 8];
  }
  __syncthreads();
  const bf16x8 qf0 = *(const bf16x8*)&Qs[(w * 16 + m16) * 72 + quad * 8];
  const bf16x8 qf1 = *(const bf16x8*)&Qs[(w * 16 + m16) * 72 + 32 + quad * 8];

  const f32x4 z4 = {0.f, 0.f, 0.f, 0.f};
  float m_r[4], l_r[4];
  f32x4 O[4];
#pragma unroll
  for (int r = 0; r < 4; r++) { m_r[r] = -1e30f; l_r[r] = 0.f; }
#pragma unroll
  for (int d = 0; d < 4; d++) O[d] = z4;

  const int qrow0 = q0 + w * 16 + quad * 4;

  for (int kt = 0; kt <= qt; ++kt) {
    const int k0 = kt * 64;
    __syncthreads();  // previous tile's Ks/Vs/Ps reads complete
    {
      const int row = tid >> 2, c = (tid & 3) * 16;
      *(u16x8*)&Ks[row * 72 + c] =
          *(const u16x8*)&kg[base + (size_t)(k0 + row) * 1024 + c];
      *(u16x8*)&Ks[row * 72 + c + 8] =
          *(const u16x8*)&kg[base + (size_t)(k0 + row) * 1024 + c + 8];
      const int key = tid & 63, dg = (tid >> 6) * 16;
      const u16x8 v0 = *(const u16x8*)&vg[base + (size_t)(k0 + key) * 1024 + dg];
      const u16x8 v1 = *(const u16x8*)&vg[base + (size_t)(k0 + key) * 1024 + dg + 8];
#pragma unroll
      for (int j = 0; j < 8; j++) {
        Vs[(dg + j) * 72 + key] = v0[j];
        Vs[(dg + 8 + j) * 72 + key] = v1[j];
      }
    }
    __syncthreads();

    // S = Q K^T
    f32x4 S[4];
#pragma unroll
    for (int nt = 0; nt < 4; nt++) {
      const bf16x8 kf0 = *(const bf16x8*)&Ks[(nt * 16 + m16) * 72 + quad * 8];
      const bf16x8 kf1 = *(const bf16x8*)&Ks[(nt * 16 + m16) * 72 + 32 + quad * 8];
      S[nt] = __builtin_amdgcn_mfma_f32_16x16x32_bf16(qf0, kf0, z4, 0, 0, 0);
      S[nt] = __builtin_amdgcn_mfma_f32_16x16x32_bf16(qf1, kf1, S[nt], 0, 0, 0);
    }

    float rowmax[4] = {-3e38f, -3e38f, -3e38f, -3e38f};
    const bool diag = (kt == qt);
#pragma unroll
    for (int nt = 0; nt < 4; nt++) {
      const int key = k0 + nt * 16 + m16;
#pragma unroll
      for (int r = 0; r < 4; r++) {
        float s = S[nt][r] * 0.03125f;  // C^-0.5 = 1/32
        if (diag && key > qrow0 + r) s = -1e30f;
        S[nt][r] = s;
        rowmax[r] = fmaxf(rowmax[r], s);
      }
    }
#pragma unroll
    for (int off = 1; off < 16; off <<= 1)
#pragma unroll
      for (int r = 0; r < 4; r++)
        rowmax[r] = fmaxf(rowmax[r], __shfl_xor(rowmax[r], off));
    float alpha[4];
#pragma unroll
    for (int r = 0; r < 4; r++) {
      const float mn = fmaxf(m_r[r], rowmax[r]);
      alpha[r] = exp2f((m_r[r] - mn) * LOG2E);
      m_r[r] = mn;
    }
    float rs[4] = {0.f, 0.f, 0.f, 0.f};
#pragma unroll
    for (int nt = 0; nt < 4; nt++)
#pragma unroll
      for (int r = 0; r < 4; r++) {
        const float p = exp2f((S[nt][r] - m_r[r]) * LOG2E);
        S[nt][r] = p;
        rs[r] += p;
      }
#pragma unroll
    for (int off = 1; off < 16; off <<= 1)
#pragma unroll
      for (int r = 0; r < 4; r++) rs[r] += __shfl_xor(rs[r], off);
#pragma unroll
    for (int r = 0; r < 4; r++) l_r[r] = l_r[r] * alpha[r] + rs[r];

    // P (C-layout) -> LDS -> A-layout for PV
#pragma unroll
    for (int nt = 0; nt < 4; nt++)
#pragma unroll
      for (int r = 0; r < 4; r++)
        Ps[(w * 16 + quad * 4 + r) * 72 + nt * 16 + m16] = f2bf(S[nt][r]);
#pragma unroll
    for (int d = 0; d < 4; d++)
#pragma unroll
      for (int r = 0; r < 4; r++) O[d][r] *= alpha[r];
    __syncthreads();

    const bf16x8 pf0 = *(const bf16x8*)&Ps[(w * 16 + m16) * 72 + quad * 8];
    const bf16x8 pf1 = *(const bf16x8*)&Ps[(w * 16 + m16) * 72 + 32 + quad * 8];
#pragma unroll
    for (int dt = 0; dt < 4; dt++) {
      const bf16x8 vf0 = *(const bf16x8*)&Vs[(dt * 16 + m16) * 72 + quad * 8];
      const bf16x8 vf1 = *(const bf16x8*)&Vs[(dt * 16 + m16) * 72 + 32 + quad * 8];
      O[dt] = __builtin_amdgcn_mfma_f32_16x16x32_bf16(pf0, vf0, O[dt], 0, 0, 0);
      O[dt] = __builtin_amdgcn_mfma_f32_16x16x32_bf16(pf1, vf1, O[dt], 0, 0, 0);
    }
  }

  // epilogue: O / l, *** f32 store *** (output dtype is float32!)
#pragma unroll
  for (int dt = 0; dt < 4; dt++)
#pragma unroll
    for (int r = 0; r < 4; r++)
      out[base + (size_t)(qrow0 + r) * 1024 + dt * 16 + m16] =
          O[dt][r] / l_r[r];
}

extern "C" void kernel_launch(void* const* d_in, const int* in_sizes, int n_in,
                              void* d_out, int out_size, void* d_ws, size_t ws_size,
                              hipStream_t stream) {
  const float* x  = (const float*)d_in[0];
  const float* Wq = (const float*)d_in[1];
  const float* Wk = (const float*)d_in[2];
  const float* Wv = (const float*)d_in[3];
  u16* qb  = (u16*)d_ws;                       // 4096x1024 bf16
  u16* kb  = qb  + (size_t)4096 * 1024;
  u16* vb  = kb  + (size_t)4096 * 1024;
  u16* xc  = vb  + (size_t)4096 * 1024;        // bf16 copies of inputs
  u16* wqc = xc  + (size_t)4096 * 1024;
  u16* wkc = wqc + (size_t)1024 * 1024;
  u16* wvc = wkc + (size_t)1024 * 1024;

  f32_to_bf16<<<dim3(2048, 4), 256, 0, stream>>>(x, Wq, Wk, Wv,
                                                 xc, wqc, wkc, wvc);
  qkv_gemm<<<dim3(8, 32, 3), 256, 0, stream>>>(xc, wqc, wkc, wvc, qb, kb, vb);
  rope_inplace<<<dim3(8192, 2), 256, 0, stream>>>(qb, kb);
  flash_attn<<<dim3(32, 16, 2), 256, 0, stream>>>(qb, kb, vb, (float*)d_out);
}